// Round 12
// baseline (19.956 us; speedup 1.0000x reference)
//
#include <hip/hip_runtime.h>
#include <math.h>

// Sliding-window (n=64) temperature-softmax attention, fp32, N=4194304.
// Round 12: REGISTER-ONLY, NO-BARRIER kernel. Accounting from R3/R5/R10:
// headline 17.5 = 5 fixed + ~6 warm compute + ~5.4 cold-L3 input read that the
// stage->__syncthreads->compute structure serializes (ws-poison fill flushes L3
// before every timed replay). Fix: drop LDS+barrier; 24 strided float4 loads
// per thread issue up-front (R4 proved strided==coalesced here, L2 absorbs the
// 3x re-read), scan runs from registers, waves overlap loads with compute.
// STEP: v-domain 2-exp (8 VALU + 2 trans; trans pipe proven free in R10).

#define SEG 32
#define PADV -1.0e30f   // pad sentinel: exp2((PADV-real)*C) == 0, self-cleaning

typedef float f32x32 __attribute__((ext_vector_type(32)));

__device__ __forceinline__ float fexp2(float x) { return __builtin_amdgcn_exp2f(x); }

__global__ __launch_bounds__(256) void soft_attn_kernel(
    const float* __restrict__ x, const float* __restrict__ w_tau,
    float* __restrict__ out)
{
    const int s = blockIdx.x * blockDim.x + threadIdx.x;   // segment id

    const float tau = log1pf(expf(w_tau[0])) + 1e-5f;
    const float C   = 1.4426950408889634f / tau;           // log2(e)/tau

    // ---- Load segs s-2 (A), s-1 (B), s (E): 24 float4, all issued up front.
    float4 A[8], B[8], E[8];
    {
        const float4* xp = reinterpret_cast<const float4*>(x) + (size_t)s * 8;
#pragma unroll
        for (int c = 0; c < 8; ++c) E[c] = xp[c];
    }
    if (s >= 2) {   // uniform branch except 2 lanes of wave 0 of block 0
        const float4* xp = reinterpret_cast<const float4*>(x) + (size_t)(s - 2) * 8;
#pragma unroll
        for (int c = 7; c >= 0; --c) A[c] = xp[c];     // suffix scan consumes A[7] first
#pragma unroll
        for (int c = 0; c < 8; ++c) B[c] = xp[8 + c];
    } else {
        const float4 pad = make_float4(PADV, PADV, PADV, PADV);
#pragma unroll
        for (int c = 0; c < 8; ++c) A[c] = pad;
        if (s == 1) {
            const float4* xp = reinterpret_cast<const float4*>(x);
#pragma unroll
            for (int c = 0; c < 8; ++c) B[c] = xp[c];
        } else {
#pragma unroll
            for (int c = 0; c < 8; ++c) B[c] = pad;
        }
    }

    // v-domain online-softmax append: exact diff then *C (absmax~0), 2 exp2.
#define STEP(val, M, R0, R1)                                   \
    {                                                          \
        const float _v  = (val);                               \
        const float _nm = fmaxf((M), _v);                      \
        const float _ea = fexp2((_v - _nm) * C);               \
        const float _eb = fexp2(((M) - _nm) * C);              \
        (R0) = fmaf((R0), _eb, _ea);                           \
        (R1) = fmaf((R1), _eb, _v * _ea);                      \
        (M)  = _nm;                                            \
    }

    // ---- Suffix scan over A (seg s-2), backwards; slot p = scan of [p+1..31].
    f32x32 Sm, Sa, Sb;
    {
        float sm = PADV, sa = 0.f, sb = 0.f;
        Sm[31] = PADV; Sa[31] = 0.f; Sb[31] = 0.f;
#pragma unroll
        for (int c = 7; c >= 0; --c) {
            STEP(A[c].w, sm, sa, sb); Sm[4*c+2] = sm; Sa[4*c+2] = sa; Sb[4*c+2] = sb;
            STEP(A[c].z, sm, sa, sb); Sm[4*c+1] = sm; Sa[4*c+1] = sa; Sb[4*c+1] = sb;
            STEP(A[c].y, sm, sa, sb); Sm[4*c+0] = sm; Sa[4*c+0] = sa; Sb[4*c+0] = sb;
            if (c > 0) { STEP(A[c].x, sm, sa, sb); Sm[4*c-1] = sm; Sa[4*c-1] = sa; Sb[4*c-1] = sb; }
        }
    }

    // ---- Prefix scan over B (seg s-1), full 32 elements.
    float m = PADV, r0 = 0.f, r1 = 0.f;
#pragma unroll
    for (int c = 0; c < 8; ++c) {
        STEP(B[c].x, m, r0, r1); STEP(B[c].y, m, r0, r1);
        STEP(B[c].z, m, r0, r1); STEP(B[c].w, m, r0, r1);
    }

    // ---- Emission over E (seg s): continue prefix, combine with suffix triples.
    float4* o4 = reinterpret_cast<float4*>(out + (size_t)s * SEG);
#pragma unroll
    for (int c = 0; c < 8; ++c) {
        float4 ob;
#pragma unroll
        for (int j = 0; j < 4; ++j) {
            const int p = 4 * c + j;
            const float val = (j == 0) ? E[c].x : (j == 1) ? E[c].y : (j == 2) ? E[c].z : E[c].w;
            STEP(val, m, r0, r1);
            const float smv = Sm[p];
            const float mm  = fmaxf(m, smv);
            const float e1  = fexp2((m   - mm) * C);
            const float e2  = fexp2((smv - mm) * C);
            const float t0  = fmaf(r0, e1, Sa[p] * e2);
            const float t1  = fmaf(r1, e1, Sb[p] * e2);
            const float res = t1 * __builtin_amdgcn_rcpf(t0);   // t0 in [1,64]
            if      (j == 0) ob.x = res;
            else if (j == 1) ob.y = res;
            else if (j == 2) ob.z = res;
            else             ob.w = res;
        }
        o4[c] = ob;
    }
#undef STEP
}

extern "C" void kernel_launch(void* const* d_in, const int* in_sizes, int n_in,
                              void* d_out, int out_size, void* d_ws, size_t ws_size,
                              hipStream_t stream) {
    const float* x = (const float*)d_in[0];
    const float* w = (const float*)d_in[1];
    float* outp = (float*)d_out;
    const int N = in_sizes[0];                 // 4194304
    const int nseg = N / SEG;                  // 131072
    const int threads = 256;
    const int blocks = nseg / threads;         // 512
    soft_attn_kernel<<<blocks, threads, 0, stream>>>(x, w, outp);
}

// Round 13
// 17.838 us; speedup vs baseline: 1.1187x; 1.1187x over previous
//
#include <hip/hip_runtime.h>
#include <math.h>

// Sliding-window (n=64) temperature-softmax attention, fp32, N=4194304.
// Round 13: R9 structure + BRANCH-FREE CLUSTERED STAGING.
// Accounting (R3/R5/R10): headline = ~5us fixed + E_cold ~12.3us, but warm rep
// = 4.6us. The 7.7us cold gap = 9 staging loads serialized by per-iteration
// per-lane guards (exec-mask dance blocks vmem clustering) + barrier-serial
// cold read. Fix: clamp indices (always in-bounds), issue all 9 loads
// back-to-back, patch block-0 halo via sentinel after, tau chain overlaps.

#define SEG 32
#define BLK 256
#define ROWS (BLK + 2)        // 258 segments: [S0-2, S0+255]
#define RSTRIDE 36            // 32 data + 4 pad floats per LDS row
#define NV4 (ROWS * (SEG/4))  // 2064 float4 in staged region
#define PADV -1.0e30f         // pad sentinel: exp2((PADV-real)*C) == 0

typedef float f32x32 __attribute__((ext_vector_type(32)));

__device__ __forceinline__ float fexp2(float x) { return __builtin_amdgcn_exp2f(x); }

__global__ __launch_bounds__(256) void soft_attn_kernel(
    const float* __restrict__ x, const float* __restrict__ w_tau,
    float* __restrict__ out)
{
    __shared__ float lds[ROWS * RSTRIDE];   // 37152 B

    const int tid = threadIdx.x;
    const int S0  = blockIdx.x * BLK;
    const int s   = S0 + tid;

    const float wt = w_tau[0];              // scalar load issued first

    // ---- Phase 1: all 9 staging loads, clamped in-bounds, ZERO branches.
    const float4* x4 = reinterpret_cast<const float4*>(x);
    const int base4 = (S0 - 2) * (SEG / 4);
    float4 t[9];
#pragma unroll
    for (int it = 0; it < 9; ++it) {
        int i = tid + it * BLK;
        i  = (i < NV4) ? i : (NV4 - 1);     // tail clamp (bites only at it==8)
        int g4 = base4 + i;
        g4 = (g4 >= 0) ? g4 : 0;            // halo clamp (bites only block 0, it==0)
        t[it] = x4[g4];                     // always valid -> clustered vmem
    }

    // tau chain hides under the in-flight loads
    const float tau = log1pf(expf(wt)) + 1e-5f;
    const float C   = 1.4426950408889634f / tau;   // log2(e)/tau

    // block-0 halo: lanes whose it=0 index was pre-start get the PAD sentinel
    if (base4 + tid < 0)
        t[0] = make_float4(PADV, PADV, PADV, PADV);

    // ---- Phase 2: ds_writes (single vmcnt drain region, pipelined by compiler)
#pragma unroll
    for (int it = 0; it < 8; ++it) {
        const int i = tid + it * BLK;
        const int r = i >> 3, c = i & 7;
        *reinterpret_cast<float4*>(&lds[r * RSTRIDE + c * 4]) = t[it];
    }
    {   // tail: only 16 lanes carry live data
        const int i = tid + 8 * BLK;
        if (i < NV4) {
            const int r = i >> 3, c = i & 7;
            *reinterpret_cast<float4*>(&lds[r * RSTRIDE + c * 4]) = t[8];
        }
    }
    __syncthreads();

    // v-domain online-softmax append: 2-exp fmaf form (absmax 0.0 per R12).
#define STEP(val, M, R0, R1)                                   \
    {                                                          \
        const float _v  = (val);                               \
        const float _nm = fmaxf((M), _v);                      \
        const float _ea = fexp2((_v - _nm) * C);               \
        const float _eb = fexp2(((M) - _nm) * C);              \
        (R0) = fmaf((R0), _eb, _ea);                           \
        (R1) = fmaf((R1), _eb, _v * _ea);                      \
        (M)  = _nm;                                            \
    }

    // ---- Suffix scan over seg s-2 (LDS row tid), backwards; slot p = [p+1..31].
    f32x32 Sm, Sa, Sb;
    {
        const float* row0 = &lds[tid * RSTRIDE];
        float sm = PADV, sa = 0.f, sb = 0.f;
        Sm[31] = PADV; Sa[31] = 0.f; Sb[31] = 0.f;
#pragma unroll
        for (int c = 7; c >= 0; --c) {
            const float4 v = *reinterpret_cast<const float4*>(row0 + 4 * c);
            STEP(v.w, sm, sa, sb); Sm[4*c+2] = sm; Sa[4*c+2] = sa; Sb[4*c+2] = sb;
            STEP(v.z, sm, sa, sb); Sm[4*c+1] = sm; Sa[4*c+1] = sa; Sb[4*c+1] = sb;
            STEP(v.y, sm, sa, sb); Sm[4*c+0] = sm; Sa[4*c+0] = sa; Sb[4*c+0] = sb;
            if (c > 0) { STEP(v.x, sm, sa, sb); Sm[4*c-1] = sm; Sa[4*c-1] = sa; Sb[4*c-1] = sb; }
        }
    }

    // ---- Prefix scan over seg s-1 (LDS row tid+1), full 32 elements.
    float m = PADV, r0 = 0.f, r1 = 0.f;
    {
        const float* row1 = &lds[(tid + 1) * RSTRIDE];
#pragma unroll
        for (int c = 0; c < 8; ++c) {
            const float4 v = *reinterpret_cast<const float4*>(row1 + 4 * c);
            STEP(v.x, m, r0, r1); STEP(v.y, m, r0, r1);
            STEP(v.z, m, r0, r1); STEP(v.w, m, r0, r1);
        }
    }

    // ---- Emission over seg s (LDS row tid+2): continue prefix + suffix combine.
    const float* row2 = &lds[(tid + 2) * RSTRIDE];
    float4* o4 = reinterpret_cast<float4*>(out + (size_t)s * SEG);
#pragma unroll
    for (int c = 0; c < 8; ++c) {
        const float4 v = *reinterpret_cast<const float4*>(row2 + 4 * c);
        float4 ob;
#pragma unroll
        for (int j = 0; j < 4; ++j) {
            const int p = 4 * c + j;
            const float val = (j == 0) ? v.x : (j == 1) ? v.y : (j == 2) ? v.z : v.w;
            STEP(val, m, r0, r1);
            const float smv = Sm[p];
            const float mm  = fmaxf(m, smv);
            const float e1  = fexp2((m   - mm) * C);
            const float e2  = fexp2((smv - mm) * C);
            const float t0  = fmaf(r0, e1, Sa[p] * e2);
            const float t1  = fmaf(r1, e1, Sb[p] * e2);
            const float res = t1 * __builtin_amdgcn_rcpf(t0);   // t0 in [1,64]
            if      (j == 0) ob.x = res;
            else if (j == 1) ob.y = res;
            else if (j == 2) ob.z = res;
            else             ob.w = res;
        }
        o4[c] = ob;
    }
#undef STEP
}

extern "C" void kernel_launch(void* const* d_in, const int* in_sizes, int n_in,
                              void* d_out, int out_size, void* d_ws, size_t ws_size,
                              hipStream_t stream) {
    const float* x = (const float*)d_in[0];
    const float* w = (const float*)d_in[1];
    float* outp = (float*)d_out;
    const int N = in_sizes[0];                 // 4194304
    const int nseg = N / SEG;                  // 131072
    const int blocks = nseg / BLK;             // 512
    soft_attn_kernel<<<blocks, BLK, 0, stream>>>(x, w, outp);
}